// Round 1
// baseline (1149.350 us; speedup 1.0000x reference)
//
#include <hip/hip_runtime.h>

// ---------------------------------------------------------------------------
// BEV encoder: points->BEV scatter + 3x (conv3x3 SAME + BN + ReLU)
// ---------------------------------------------------------------------------

constexpr int BEVW = 250;
constexpr int SZC  = BEVW * BEVW;   // 62500 cells

__device__ __forceinline__ unsigned f2ord(float f) {
    unsigned u = __float_as_uint(f);
    return (u & 0x80000000u) ? ~u : (u | 0x80000000u);
}
__device__ __forceinline__ float ord2f(unsigned u) {
    unsigned b = (u & 0x80000000u) ? (u & 0x7FFFFFFFu) : ~u;
    return __uint_as_float(b);
}

// ---- init accumulators --------------------------------------------------
__global__ void k_init(unsigned* __restrict__ mx, unsigned* __restrict__ mn,
                       float* __restrict__ dn, float* __restrict__ si) {
    int i = blockIdx.x * blockDim.x + threadIdx.x;
    if (i < SZC) {
        mx[i] = 0u;            // below any mapped real
        mn[i] = 0xFFFFFFFFu;   // above any mapped real
        dn[i] = 0.0f;
        si[i] = 0.0f;
    }
}

// ---- scatter points -----------------------------------------------------
__global__ void k_scatter(const float4* __restrict__ pts, int n,
                          unsigned* __restrict__ mx, unsigned* __restrict__ mn,
                          float* __restrict__ dn, float* __restrict__ si) {
    int i = blockIdx.x * blockDim.x + threadIdx.x;
    if (i >= n) return;
    float4 p = pts[i];
    float x = p.x, y = p.y, z = p.z, it = p.w;
    bool valid = (x >= -50.0f) && (x < 50.0f) && (y >= -50.0f) && (y < 50.0f);
    if (!valid) return;
    // must match JAX/np f32 semantics exactly: IEEE f32 add, IEEE f32 div,
    // truncating cast, clip.
    int xi = (int)((x + 50.0f) / 0.4f);
    int yi = (int)((y + 50.0f) / 0.4f);
    xi = min(max(xi, 0), BEVW - 1);
    yi = min(max(yi, 0), BEVW - 1);
    int cell = yi * BEVW + xi;
    unsigned zo = f2ord(z);
    atomicMax(&mx[cell], zo);
    atomicMin(&mn[cell], zo);
    atomicAdd(&dn[cell], 1.0f);
    atomicAdd(&si[cell], it);
}

// ---- finalize BEV -------------------------------------------------------
__global__ void k_finalize(const unsigned* __restrict__ mx, const unsigned* __restrict__ mn,
                           const float* __restrict__ dn, const float* __restrict__ si,
                           float* __restrict__ bev) {
    int i = blockIdx.x * blockDim.x + threadIdx.x;
    if (i >= SZC) return;
    float d = dn[i];
    bool has = d > 0.0f;
    bev[0 * SZC + i] = has ? ord2f(mx[i]) : 0.0f;
    bev[1 * SZC + i] = has ? ord2f(mn[i]) : 0.0f;
    bev[2 * SZC + i] = log1pf(d);
    bev[3 * SZC + i] = has ? si[i] / d : 0.0f;
}

// ---- conv 3x3 SAME, direct, tiled ---------------------------------------
// in:  [CIN][250][250], w: [COUT][CIN][3][3], out: [COUT][250][250]
// grid: (256 tiles, COUT/OCG); block: 256 (16x16 pixels)
template <int CIN, int ICB, int OCG>
__launch_bounds__(256)
__global__ void k_conv3x3(const float* __restrict__ in, const float* __restrict__ w,
                          const float* __restrict__ bias, float* __restrict__ out) {
    __shared__ float s_in[ICB][18][18];
    __shared__ __align__(16) float s_w[ICB][9][OCG];

    const int tid = threadIdx.x;
    const int px = tid & 15, py = tid >> 4;
    const int tile = blockIdx.x;              // 0..255
    const int tx = (tile & 15) * 16, ty = (tile >> 4) * 16;
    const int oc0 = blockIdx.y * OCG;

    float acc[OCG];
#pragma unroll
    for (int o = 0; o < OCG; ++o) acc[o] = 0.0f;

    for (int ic0 = 0; ic0 < CIN; ic0 += ICB) {
        __syncthreads();
        // stage input tile with halo, zero-padded
        for (int e = tid; e < ICB * 18 * 18; e += 256) {
            int c = e / 324, r = (e % 324) / 18, q = e % 18;
            int gy = ty - 1 + r, gx = tx - 1 + q;
            float v = 0.0f;
            if (gy >= 0 && gy < BEVW && gx >= 0 && gx < BEVW)
                v = in[(ic0 + c) * SZC + gy * BEVW + gx];
            s_in[c][r][q] = v;
        }
        // stage weights as [icl][k][oc] so 16 oc weights are contiguous
        for (int e = tid; e < ICB * 9 * OCG; e += 256) {
            int ocl = e & (OCG - 1);
            int k   = (e / OCG) % 9;
            int icl = e / (OCG * 9);
            s_w[icl][k][ocl] = w[(oc0 + ocl) * CIN * 9 + (ic0 + icl) * 9 + k];
        }
        __syncthreads();

#pragma unroll
        for (int icl = 0; icl < ICB; ++icl) {
#pragma unroll
            for (int k = 0; k < 9; ++k) {
                float v = s_in[icl][py + k / 3][px + k % 3];
                const float4* wp = reinterpret_cast<const float4*>(&s_w[icl][k][0]);
#pragma unroll
                for (int j = 0; j < OCG / 4; ++j) {
                    float4 wv = wp[j];
                    acc[j * 4 + 0] = fmaf(v, wv.x, acc[j * 4 + 0]);
                    acc[j * 4 + 1] = fmaf(v, wv.y, acc[j * 4 + 1]);
                    acc[j * 4 + 2] = fmaf(v, wv.z, acc[j * 4 + 2]);
                    acc[j * 4 + 3] = fmaf(v, wv.w, acc[j * 4 + 3]);
                }
            }
        }
    }

    int ox = tx + px, oy = ty + py;
    if (ox < BEVW && oy < BEVW) {
#pragma unroll
        for (int o = 0; o < OCG; ++o)
            out[(oc0 + o) * SZC + oy * BEVW + ox] = acc[o] + bias[oc0 + o];
    }
}

// ---- BN stats: one block per channel ------------------------------------
__global__ void k_bnstats(const float* __restrict__ y, float* __restrict__ stats) {
    int c = blockIdx.x;
    const float* p = y + (size_t)c * SZC;
    double s = 0.0, s2 = 0.0;
    for (int i = threadIdx.x; i < SZC; i += 256) {
        float v = p[i];
        s += (double)v;
        s2 += (double)v * (double)v;
    }
    for (int off = 32; off; off >>= 1) {
        s  += __shfl_down(s, off);
        s2 += __shfl_down(s2, off);
    }
    __shared__ double sh[8];
    int wid = threadIdx.x >> 6;
    if ((threadIdx.x & 63) == 0) { sh[wid * 2] = s; sh[wid * 2 + 1] = s2; }
    __syncthreads();
    if (threadIdx.x == 0) {
        double S = 0.0, S2 = 0.0;
        for (int wv = 0; wv < 4; ++wv) { S += sh[wv * 2]; S2 += sh[wv * 2 + 1]; }
        double mu  = S / (double)SZC;
        double var = S2 / (double)SZC - mu * mu;
        stats[c * 2]     = (float)mu;
        stats[c * 2 + 1] = (float)(1.0 / sqrt(var + 1e-5));
    }
}

// ---- BN apply + ReLU (per-channel grid.y) --------------------------------
__global__ void k_bnrelu(const float* __restrict__ y, const float* __restrict__ stats,
                         const float* __restrict__ g, const float* __restrict__ beta,
                         float* __restrict__ out) {
    int c = blockIdx.y;
    int i = blockIdx.x * blockDim.x + threadIdx.x;
    if (i >= SZC) return;
    float mu = stats[c * 2], rs = stats[c * 2 + 1];
    size_t idx = (size_t)c * SZC + i;
    float v = (y[idx] - mu) * rs * g[c] + beta[c];
    out[idx] = v > 0.0f ? v : 0.0f;
}

// ---------------------------------------------------------------------------
extern "C" void kernel_launch(void* const* d_in, const int* in_sizes, int n_in,
                              void* d_out, int out_size, void* d_ws, size_t ws_size,
                              hipStream_t stream) {
    const float4* pts = (const float4*)d_in[0];
    const float* w1 = (const float*)d_in[1];
    const float* b1 = (const float*)d_in[2];
    const float* g1 = (const float*)d_in[3];
    const float* be1 = (const float*)d_in[4];
    const float* w2 = (const float*)d_in[5];
    const float* b2 = (const float*)d_in[6];
    const float* g2 = (const float*)d_in[7];
    const float* be2 = (const float*)d_in[8];
    const float* w3 = (const float*)d_in[9];
    const float* b3 = (const float*)d_in[10];
    const float* g3 = (const float*)d_in[11];
    const float* be3 = (const float*)d_in[12];

    float* ws = (float*)d_ws;
    unsigned* mx = (unsigned*)ws;            // 62500
    unsigned* mn = mx + SZC;                 // 62500
    float* dn  = ws + 2 * SZC;               // 62500
    float* si  = ws + 3 * SZC;               // 62500
    float* bev = ws + 4 * SZC;               // 4*62500
    float* y1  = ws + 8 * SZC;               // 32*62500
    float* y2  = ws + 40 * SZC;              // 64*62500
    float* st1 = ws + 104 * SZC;             // 64 floats
    float* st2 = st1 + 64;                   // 128
    float* st3 = st2 + 128;                  // 128
    float* out = (float*)d_out;              // 64*62500

    int n = in_sizes[0] / 4;                 // 5,000,000 points

    const int cellBlocks = (SZC + 255) / 256;

    k_init<<<cellBlocks, 256, 0, stream>>>(mx, mn, dn, si);
    k_scatter<<<(n + 255) / 256, 256, 0, stream>>>(pts, n, mx, mn, dn, si);
    k_finalize<<<cellBlocks, 256, 0, stream>>>(mx, mn, dn, si, bev);

    // layer 1: 4 -> 32
    k_conv3x3<4, 4, 16><<<dim3(256, 2), 256, 0, stream>>>(bev, w1, b1, y1);
    k_bnstats<<<32, 256, 0, stream>>>(y1, st1);
    k_bnrelu<<<dim3(cellBlocks, 32), 256, 0, stream>>>(y1, st1, g1, be1, y1);

    // layer 2: 32 -> 64
    k_conv3x3<32, 8, 16><<<dim3(256, 4), 256, 0, stream>>>(y1, w2, b2, y2);
    k_bnstats<<<64, 256, 0, stream>>>(y2, st2);
    k_bnrelu<<<dim3(cellBlocks, 64), 256, 0, stream>>>(y2, st2, g2, be2, y2);

    // layer 3: 64 -> 64 (write straight to d_out)
    k_conv3x3<64, 8, 16><<<dim3(256, 4), 256, 0, stream>>>(y2, w3, b3, out);
    k_bnstats<<<64, 256, 0, stream>>>(out, st3);
    k_bnrelu<<<dim3(cellBlocks, 64), 256, 0, stream>>>(out, st3, g3, be3, out);
}